// Round 5
// baseline (484.070 us; speedup 1.0000x reference)
//
#include <hip/hip_runtime.h>
#include <math.h>

#define TT 2048   // tokens
#define HH 1024   // hidden
#define EE 8      // experts
#define II 2048   // intermediate
#define N1 4096   // 2*II
#define ALPHA 1.702f
#define LIMIT 7.0f

typedef __attribute__((ext_vector_type(8))) short short8;
typedef __attribute__((ext_vector_type(4))) float floatx4;
typedef __attribute__((ext_vector_type(4))) unsigned int uintx4;

__device__ __forceinline__ short f2bf(float f) {
  union { float f; unsigned u; } v; v.f = f;
  unsigned r = (v.u + 0x7fffu + ((v.u >> 16) & 1u)) >> 16;
  return (short)r;
}
// 2x f32 -> packed bf16 (RNE), lo in low 16 bits
__device__ __forceinline__ unsigned cvt2(float lo, float hi) {
  unsigned r;
  asm("v_cvt_pk_bf16_f32 %0, %1, %2" : "=v"(r) : "v"(lo), "v"(hi));
  return r;
}
// async global->LDS DMA, 16B per lane; global addr per-lane, LDS dest uniform
__device__ __forceinline__ void gload16(const void* g, void* l) {
  __builtin_amdgcn_global_load_lds(
      (const __attribute__((address_space(1))) unsigned int*)g,
      (__attribute__((address_space(3))) unsigned int*)l, 16, 0, 0);
}

// ---------------- prepass: weight [E][K][N] f32 -> [E][N][K] bf16 ----------------
__global__ __launch_bounds__(256) void transpose_bf16(
    const float* __restrict__ src, unsigned short* __restrict__ dst,
    const int K, const int N) {
  const int e = blockIdx.z;
  const int n0 = blockIdx.x * 64, k0 = blockIdx.y * 64;
  __shared__ float tile[64][68];
  const float* s = src + (size_t)e * K * N;
  unsigned short* d = dst + (size_t)e * N * K;
  const int t = threadIdx.x;
  const int nq = t & 15, kr = t >> 4;
#pragma unroll
  for (int r = 0; r < 4; r++) {
    const int k = r * 16 + kr;
    const float4 v = *(const float4*)(s + (size_t)(k0 + k) * N + n0 + nq * 4);
    tile[k][nq * 4 + 0] = v.x; tile[k][nq * 4 + 1] = v.y;
    tile[k][nq * 4 + 2] = v.z; tile[k][nq * 4 + 3] = v.w;
  }
  __syncthreads();
  const int n = t >> 2, ks = (t & 3) * 16;
  unsigned short* orow = d + (size_t)(n0 + n) * K + k0 + ks;
  uintx4 w0, w1;
#pragma unroll
  for (int m = 0; m < 4; m++)
    w0[m] = cvt2(tile[ks + 2 * m][n], tile[ks + 2 * m + 1][n]);
#pragma unroll
  for (int m = 0; m < 4; m++)
    w1[m] = cvt2(tile[ks + 8 + 2 * m][n], tile[ks + 9 + 2 * m][n]);
  *(uintx4*)orow = w0;
  *(uintx4*)(orow + 8) = w1;
}

// ------- router: logits -> softmax -> top2 -> assign; also x f32->bf16 -------
__global__ __launch_bounds__(256) void router_kernel(
    const float* __restrict__ x, const float* __restrict__ rw,
    const float* __restrict__ rb, float* __restrict__ topk_w,
    int* __restrict__ counts, int* __restrict__ rows,
    unsigned short* __restrict__ xb) {
  const int t = blockIdx.x;
  const float* xr = x + (size_t)t * HH;
  const int lane = threadIdx.x & 63;
  const int wave = threadIdx.x >> 6;
  float xv[16];
#pragma unroll
  for (int i = 0; i < 16; i++) xv[i] = xr[lane + i * 64];
  __shared__ float logits[EE];
#pragma unroll
  for (int ee = 0; ee < 2; ee++) {
    const int e = wave * 2 + ee;
    const float* wr = rw + (size_t)e * HH;
    float s = 0.f;
#pragma unroll
    for (int i = 0; i < 16; i++) s += xv[i] * wr[lane + i * 64];
#pragma unroll
    for (int off = 32; off > 0; off >>= 1) s += __shfl_down(s, off, 64);
    if (lane == 0) logits[e] = s + rb[e];
  }
  // wave 0 holds the full row across its 16 regs: convert to bf16
  if (wave == 0) {
    unsigned short* xo = xb + (size_t)t * HH;
#pragma unroll
    for (int i = 0; i < 16; i++) xo[lane + i * 64] = (unsigned short)f2bf(xv[i]);
  }
  __syncthreads();
  if (threadIdx.x == 0) {
    float l[EE], sc[EE];
    float mx = -3.4e38f;
    for (int i = 0; i < EE; i++) { l[i] = logits[i]; mx = fmaxf(mx, l[i]); }
    float sum = 0.f;
    for (int i = 0; i < EE; i++) { sc[i] = expf(l[i] - mx); sum += sc[i]; }
    const float inv = 1.f / sum;
    int i0 = 0;
    for (int i = 1; i < EE; i++) if (sc[i] > sc[i0]) i0 = i;
    int i1 = (i0 == 0) ? 1 : 0;
    for (int i = 0; i < EE; i++) if (i != i0 && sc[i] > sc[i1]) i1 = i;
    topk_w[t * 2 + 0] = sc[i0] * inv;
    topk_w[t * 2 + 1] = sc[i1] * inv;
    const int s0 = atomicAdd(&counts[i0], 1);
    rows[i0 * TT + s0] = t * 2 + 0;
    const int s1 = atomicAdd(&counts[i1], 1);
    rows[i1 * TT + s1] = t * 2 + 1;
  }
}

// ---- GEMM1 (m97-structure, 4-deep pipeline) + fused GLU -> act bf16 ----
// 4 waves, tile 128 rows x (64 gate + 64 up cols), BK=32, vmcnt(12).
__global__ __launch_bounds__(256, 2) void gemm_gu(
    const unsigned short* __restrict__ xb, const unsigned short* __restrict__ gupt,
    const float* __restrict__ gub, const int* __restrict__ counts,
    const int* __restrict__ rows, unsigned short* __restrict__ act) {
  const int e = blockIdx.z, mtile = blockIdx.y, ntile = blockIdx.x;
  const int count = counts[e];
  if (mtile * 128 >= count) return;
  const int* rl = rows + e * TT + mtile * 128;
  __shared__ __align__(16) char smem[65536];
  unsigned short* As = (unsigned short*)smem;            // [4][4096] bf16
  unsigned short* Bs = (unsigned short*)(smem + 32768);  // [4][4096] bf16
  float* glds = (float*)smem;                            // [128][65] epilogue overlay
  const int tid = threadIdx.x;
  const int lane = tid & 63, wave = tid >> 6;
  const int wm = (wave & 1) << 6, wn = (wave >> 1) << 6;
  const int quad = lane >> 4, r16 = lane & 15;

  // staging: instr q=wave*2+r covers rows q*16+(lane>>2), 16B at (lane&3)*16
  const int lrow = lane >> 2, lko = (lane & 3) * 8;
  const int q0 = wave * 2, q1 = q0 + 1;
  const int row0 = q0 * 16 + lrow, row1 = q1 * 16 + lrow;
  const int last = count - 1 - mtile * 128;
  const int cr0 = row0 <= last ? row0 : last;
  const int cr1 = row1 <= last ? row1 : last;
  const unsigned short* pA0 = xb + (size_t)(rl[cr0] >> 1) * HH + lko;
  const unsigned short* pA1 = xb + (size_t)(rl[cr1] >> 1) * HH + lko;
  const int bn0 = (row0 < 64) ? (ntile * 64 + row0) : (II + ntile * 64 + row0 - 64);
  const int bn1 = (row1 < 64) ? (ntile * 64 + row1) : (II + ntile * 64 + row1 - 64);
  const unsigned short* pB0 = gupt + (size_t)e * N1 * HH + (size_t)bn0 * HH + lko;
  const unsigned short* pB1 = gupt + (size_t)e * N1 * HH + (size_t)bn1 * HH + lko;
  unsigned short* dA0 = As + q0 * 512;  // wave-uniform LDS dests
  unsigned short* dA1 = As + q1 * 512;
  unsigned short* dB0 = Bs + q0 * 512;
  unsigned short* dB1 = Bs + q1 * 512;

  floatx4 acc[4][4] = {};
  const int NTK = HH / 32;  // 32

#define STAGE(B, kk) do { \
    const int ko_ = (kk) * 32; \
    gload16(pA0 + ko_, dA0 + (B) * 4096); \
    gload16(pA1 + ko_, dA1 + (B) * 4096); \
    gload16(pB0 + ko_, dB0 + (B) * 4096); \
    gload16(pB1 + ko_, dB1 + (B) * 4096); \
  } while (0)

#define PHASE(B) do { \
    asm volatile("s_waitcnt vmcnt(12)" ::: "memory"); \
    __builtin_amdgcn_s_barrier(); \
    short8 af[4], bf4[4]; \
    _Pragma("unroll") for (int i = 0; i < 4; i++) \
      af[i] = *(const short8*)(As + (B) * 4096 + (wm + i * 16 + r16) * 32 + quad * 8); \
    _Pragma("unroll") for (int j = 0; j < 4; j++) \
      bf4[j] = *(const short8*)(Bs + (B) * 4096 + (wn + j * 16 + r16) * 32 + quad * 8); \
    asm volatile("s_waitcnt lgkmcnt(0)" ::: "memory"); \
    __builtin_amdgcn_sched_barrier(0); \
    __builtin_amdgcn_s_barrier(); \
    { const int ks_ = kn < NTK ? kn : NTK - 1; kn++; STAGE(B, ks_); } \
    __builtin_amdgcn_sched_barrier(0); \
    __builtin_amdgcn_s_setprio(1); \
    _Pragma("unroll") for (int i = 0; i < 4; i++) \
      _Pragma("unroll") for (int j = 0; j < 4; j++) \
        acc[i][j] = __builtin_amdgcn_mfma_f32_16x16x32_bf16(af[i], bf4[j], acc[i][j], 0, 0, 0); \
    __builtin_amdgcn_s_setprio(0); \
  } while (0)

  STAGE(0, 0);
  STAGE(1, 1);
  STAGE(2, 2);
  STAGE(3, 3);
  int kn = 4;
#pragma unroll 1
  for (int t = 0; t < NTK; t += 4) {
    PHASE(0);
    PHASE(1);
    PHASE(2);
    PHASE(3);
  }
  asm volatile("s_waitcnt vmcnt(0)" ::: "memory");
  __builtin_amdgcn_s_barrier();

  // epilogue: gate waves (wn==0) -> glu to LDS; up waves -> act bf16
  const int colbase = ntile * 64;
  if (wn == 0) {
#pragma unroll
    for (int j = 0; j < 4; j++) {
      const int c = j * 16 + r16;
      const float gb = gub[e * N1 + colbase + c];
#pragma unroll
      for (int i = 0; i < 4; i++)
#pragma unroll
        for (int reg = 0; reg < 4; reg++) {
          const int rr = wm + i * 16 + quad * 4 + reg;
          float g = acc[i][j][reg] + gb;
          g = fminf(g, LIMIT);
          glds[rr * 65 + c] = g / (1.f + expf(-g * ALPHA));
        }
    }
  }
  __builtin_amdgcn_s_barrier();
  if (wn == 64) {
#pragma unroll
    for (int j = 0; j < 4; j++) {
      const int c = j * 16 + r16;
      const float ub = gub[e * N1 + II + colbase + c];
#pragma unroll
      for (int i = 0; i < 4; i++)
#pragma unroll
        for (int reg = 0; reg < 4; reg++) {
          const int rr = wm + i * 16 + quad * 4 + reg;
          if (mtile * 128 + rr < count) {
            float u = acc[i][j][reg] + ub;
            u = fminf(fmaxf(u, -LIMIT), LIMIT);
            const float glu = glds[rr * 65 + c];
            act[(size_t)rl[rr] * II + colbase + c] = (unsigned short)f2bf((u + 1.f) * glu);
          }
        }
    }
  }
#undef STAGE
#undef PHASE
}

// ---- GEMM2 (4-deep pipeline): act bf16 x dp_t bf16, split-K=2,
//      epilogue scales by topk_w and atomicAdds into out ----
__global__ __launch_bounds__(256, 2) void gemm_down(
    const unsigned short* __restrict__ act, const unsigned short* __restrict__ dpt,
    const float* __restrict__ db, const int* __restrict__ counts,
    const int* __restrict__ rows, const float* __restrict__ tw,
    float* __restrict__ out) {
  const int e = blockIdx.z >> 1, kc = blockIdx.z & 1;
  const int mtile = blockIdx.y, ntile = blockIdx.x;
  const int count = counts[e];
  if (mtile * 128 >= count) return;
  const int kb = kc * (II / 2);  // 1024-wide K chunk
  const int* rl = rows + e * TT + mtile * 128;
  __shared__ __align__(16) char smem[65536];
  unsigned short* As = (unsigned short*)smem;            // [4][4096]
  unsigned short* Bs = (unsigned short*)(smem + 32768);  // [4][4096]
  const int tid = threadIdx.x;
  const int lane = tid & 63, wave = tid >> 6;
  const int wm = (wave & 1) << 6, wn = (wave >> 1) << 6;
  const int quad = lane >> 4, r16 = lane & 15;

  const int lrow = lane >> 2, lko = (lane & 3) * 8;
  const int q0 = wave * 2, q1 = q0 + 1;
  const int row0 = q0 * 16 + lrow, row1 = q1 * 16 + lrow;
  const int last = count - 1 - mtile * 128;
  const int cr0 = row0 <= last ? row0 : last;
  const int cr1 = row1 <= last ? row1 : last;
  const unsigned short* pA0 = act + (size_t)rl[cr0] * II + kb + lko;
  const unsigned short* pA1 = act + (size_t)rl[cr1] * II + kb + lko;
  const unsigned short* pB0 = dpt + (size_t)e * HH * II + (size_t)(ntile * 128 + row0) * II + kb + lko;
  const unsigned short* pB1 = dpt + (size_t)e * HH * II + (size_t)(ntile * 128 + row1) * II + kb + lko;
  unsigned short* dA0 = As + q0 * 512;
  unsigned short* dA1 = As + q1 * 512;
  unsigned short* dB0 = Bs + q0 * 512;
  unsigned short* dB1 = Bs + q1 * 512;

  floatx4 acc[4][4] = {};
  const int NTK = (II / 2) / 32;  // 32

#define STAGE(B, kk) do { \
    const int ko_ = (kk) * 32; \
    gload16(pA0 + ko_, dA0 + (B) * 4096); \
    gload16(pA1 + ko_, dA1 + (B) * 4096); \
    gload16(pB0 + ko_, dB0 + (B) * 4096); \
    gload16(pB1 + ko_, dB1 + (B) * 4096); \
  } while (0)

#define PHASE(B) do { \
    asm volatile("s_waitcnt vmcnt(12)" ::: "memory"); \
    __builtin_amdgcn_s_barrier(); \
    short8 af[4], bf4[4]; \
    _Pragma("unroll") for (int i = 0; i < 4; i++) \
      af[i] = *(const short8*)(As + (B) * 4096 + (wm + i * 16 + r16) * 32 + quad * 8); \
    _Pragma("unroll") for (int j = 0; j < 4; j++) \
      bf4[j] = *(const short8*)(Bs + (B) * 4096 + (wn + j * 16 + r16) * 32 + quad * 8); \
    asm volatile("s_waitcnt lgkmcnt(0)" ::: "memory"); \
    __builtin_amdgcn_sched_barrier(0); \
    __builtin_amdgcn_s_barrier(); \
    { const int ks_ = kn < NTK ? kn : NTK - 1; kn++; STAGE(B, ks_); } \
    __builtin_amdgcn_sched_barrier(0); \
    __builtin_amdgcn_s_setprio(1); \
    _Pragma("unroll") for (int i = 0; i < 4; i++) \
      _Pragma("unroll") for (int j = 0; j < 4; j++) \
        acc[i][j] = __builtin_amdgcn_mfma_f32_16x16x32_bf16(af[i], bf4[j], acc[i][j], 0, 0, 0); \
    __builtin_amdgcn_s_setprio(0); \
  } while (0)

  STAGE(0, 0);
  STAGE(1, 1);
  STAGE(2, 2);
  STAGE(3, 3);
  int kn = 4;
#pragma unroll 1
  for (int t = 0; t < NTK; t += 4) {
    PHASE(0);
    PHASE(1);
    PHASE(2);
    PHASE(3);
  }
  asm volatile("s_waitcnt vmcnt(0)" ::: "memory");
  __builtin_amdgcn_s_barrier();

#pragma unroll
  for (int i = 0; i < 4; i++) {
#pragma unroll
    for (int reg = 0; reg < 4; reg++) {
      const int rr = wm + i * 16 + quad * 4 + reg;
      if (mtile * 128 + rr < count) {
        const int ent = rl[rr];
        const float w = tw[ent];
        float* orow = out + (size_t)(ent >> 1) * HH + ntile * 128;
#pragma unroll
        for (int j = 0; j < 4; j++) {
          const int c = wn + j * 16 + r16;
          float v = acc[i][j][reg];
          if (kc == 0) v += db[e * HH + ntile * 128 + c];
          atomicAdd(&orow[c], w * v);
        }
      }
    }
  }
#undef STAGE
#undef PHASE
}

extern "C" void kernel_launch(void* const* d_in, const int* in_sizes, int n_in,
                              void* d_out, int out_size, void* d_ws, size_t ws_size,
                              hipStream_t stream) {
  const float* x   = (const float*)d_in[0];
  const float* rw  = (const float*)d_in[1];
  const float* rb  = (const float*)d_in[2];
  const float* gup = (const float*)d_in[3];
  const float* gub = (const float*)d_in[4];
  const float* dp  = (const float*)d_in[5];
  const float* db  = (const float*)d_in[6];
  float* out = (float*)d_out;

  char* ws = (char*)d_ws;
  float* topk_w   = (float*)(ws + 0);                      // 16 KB
  int*   counts   = (int*)(ws + 16384);                    // 256 B
  int*   rows     = (int*)(ws + 16640);                    // 64 KB
  unsigned short* xb   = (unsigned short*)(ws + 131072);               // 4 MB
  unsigned short* gupt = (unsigned short*)(ws + 4325376);              // 67.1 MB
  unsigned short* dpt  = (unsigned short*)(ws + 71434240);             // 33.6 MB
  unsigned short* act  = (unsigned short*)(ws + 104988672);            // 16.8 MB

  hipMemsetAsync(counts, 0, 64, stream);
  hipMemsetAsync(out, 0, (size_t)TT * HH * 4, stream);
  router_kernel<<<TT, 256, 0, stream>>>(x, rw, rb, topk_w, counts, rows, xb);
  transpose_bf16<<<dim3(N1 / 64, HH / 64, EE), 256, 0, stream>>>(gup, gupt, HH, N1);
  transpose_bf16<<<dim3(HH / 64, II / 64, EE), 256, 0, stream>>>(dp, dpt, II, HH);
  gemm_gu<<<dim3(II / 64, TT / 128, EE), 256, 0, stream>>>(xb, gupt, gub, counts, rows, act);
  gemm_down<<<dim3(HH / 128, TT / 128, EE * 2), 256, 0, stream>>>(act, dpt, db, counts, rows, topk_w, out);
}

// Round 6
// 477.081 us; speedup vs baseline: 1.0146x; 1.0146x over previous
//
#include <hip/hip_runtime.h>
#include <math.h>

#define TT 2048   // tokens
#define HH 1024   // hidden
#define EE 8      // experts
#define II 2048   // intermediate
#define N1 4096   // 2*II
#define ALPHA 1.702f
#define LIMIT 7.0f

typedef __attribute__((ext_vector_type(8))) short short8;
typedef __attribute__((ext_vector_type(4))) float floatx4;
typedef __attribute__((ext_vector_type(4))) unsigned int uintx4;

__device__ __forceinline__ short f2bf(float f) {
  union { float f; unsigned u; } v; v.f = f;
  unsigned r = (v.u + 0x7fffu + ((v.u >> 16) & 1u)) >> 16;
  return (short)r;
}
// 2x f32 -> packed bf16 (RNE), lo in low 16 bits
__device__ __forceinline__ unsigned cvt2(float lo, float hi) {
  unsigned r;
  asm("v_cvt_pk_bf16_f32 %0, %1, %2" : "=v"(r) : "v"(lo), "v"(hi));
  return r;
}
// async global->LDS DMA, 16B per lane; global addr per-lane, LDS dest uniform
__device__ __forceinline__ void gload16(const void* g, void* l) {
  __builtin_amdgcn_global_load_lds(
      (const __attribute__((address_space(1))) unsigned int*)g,
      (__attribute__((address_space(3))) unsigned int*)l, 16, 0, 0);
}

// ------ prepass (ONE dispatch): both weights [E][K][N] f32 -> [E][N][K] bf16;
//        block 0 also zeroes counts ------
__global__ __launch_bounds__(256) void transpose_all(
    const float* __restrict__ gup, const float* __restrict__ dp,
    unsigned short* __restrict__ gupt, unsigned short* __restrict__ dpt,
    int* __restrict__ counts) {
  const int id = blockIdx.x;
  if (id == 0 && threadIdx.x < 16) counts[threadIdx.x] = 0;
  const float* src;
  unsigned short* dst;
  int K, N, n0, k0, e;
  if (id < 8192) {  // gup: N1/64=64 x HH/64=16 x 8
    src = gup; dst = gupt; K = HH; N = N1;
    n0 = (id & 63) * 64; k0 = ((id >> 6) & 15) * 64; e = id >> 10;
  } else {          // dp: HH/64=16 x II/64=32 x 8
    const int id2 = id - 8192;
    src = dp; dst = dpt; K = II; N = HH;
    n0 = (id2 & 15) * 64; k0 = ((id2 >> 4) & 31) * 64; e = id2 >> 9;
  }
  __shared__ float tile[64][68];
  const float* s = src + (size_t)e * K * N;
  unsigned short* d = dst + (size_t)e * N * K;
  const int t = threadIdx.x;
  const int nq = t & 15, kr = t >> 4;
#pragma unroll
  for (int r = 0; r < 4; r++) {
    const int k = r * 16 + kr;
    const float4 v = *(const float4*)(s + (size_t)(k0 + k) * N + n0 + nq * 4);
    tile[k][nq * 4 + 0] = v.x; tile[k][nq * 4 + 1] = v.y;
    tile[k][nq * 4 + 2] = v.z; tile[k][nq * 4 + 3] = v.w;
  }
  __syncthreads();
  const int n = t >> 2, ks = (t & 3) * 16;
  unsigned short* orow = d + (size_t)(n0 + n) * K + k0 + ks;
  uintx4 w0, w1;
#pragma unroll
  for (int m = 0; m < 4; m++)
    w0[m] = cvt2(tile[ks + 2 * m][n], tile[ks + 2 * m + 1][n]);
#pragma unroll
  for (int m = 0; m < 4; m++)
    w1[m] = cvt2(tile[ks + 8 + 2 * m][n], tile[ks + 9 + 2 * m][n]);
  *(uintx4*)orow = w0;
  *(uintx4*)(orow + 8) = w1;
}

// --- router: logits -> softmax -> top2 -> assign; x f32->bf16; zero out row ---
__global__ __launch_bounds__(256) void router_kernel(
    const float* __restrict__ x, const float* __restrict__ rw,
    const float* __restrict__ rb, float* __restrict__ topk_w,
    int* __restrict__ counts, int* __restrict__ rows,
    unsigned short* __restrict__ xb, float* __restrict__ out) {
  const int t = blockIdx.x;
  const float* xr = x + (size_t)t * HH;
  const int lane = threadIdx.x & 63;
  const int wave = threadIdx.x >> 6;
  // zero this token's output row (gemm_down atomicAdds into it later)
  const float4 z = {0.f, 0.f, 0.f, 0.f};
  ((float4*)(out + (size_t)t * HH))[threadIdx.x] = z;
  float xv[16];
#pragma unroll
  for (int i = 0; i < 16; i++) xv[i] = xr[lane + i * 64];
  __shared__ float logits[EE];
#pragma unroll
  for (int ee = 0; ee < 2; ee++) {
    const int e = wave * 2 + ee;
    const float* wr = rw + (size_t)e * HH;
    float s = 0.f;
#pragma unroll
    for (int i = 0; i < 16; i++) s += xv[i] * wr[lane + i * 64];
#pragma unroll
    for (int off = 32; off > 0; off >>= 1) s += __shfl_down(s, off, 64);
    if (lane == 0) logits[e] = s + rb[e];
  }
  // wave 0 holds the full row across its 16 regs: convert to bf16
  if (wave == 0) {
    unsigned short* xo = xb + (size_t)t * HH;
#pragma unroll
    for (int i = 0; i < 16; i++) xo[lane + i * 64] = (unsigned short)f2bf(xv[i]);
  }
  __syncthreads();
  if (threadIdx.x == 0) {
    float l[EE], sc[EE];
    float mx = -3.4e38f;
    for (int i = 0; i < EE; i++) { l[i] = logits[i]; mx = fmaxf(mx, l[i]); }
    float sum = 0.f;
    for (int i = 0; i < EE; i++) { sc[i] = expf(l[i] - mx); sum += sc[i]; }
    const float inv = 1.f / sum;
    int i0 = 0;
    for (int i = 1; i < EE; i++) if (sc[i] > sc[i0]) i0 = i;
    int i1 = (i0 == 0) ? 1 : 0;
    for (int i = 0; i < EE; i++) if (i != i0 && sc[i] > sc[i1]) i1 = i;
    topk_w[t * 2 + 0] = sc[i0] * inv;
    topk_w[t * 2 + 1] = sc[i1] * inv;
    const int s0 = atomicAdd(&counts[i0], 1);
    rows[i0 * TT + s0] = t * 2 + 0;
    const int s1 = atomicAdd(&counts[i1], 1);
    rows[i1 * TT + s1] = t * 2 + 1;
  }
}

// ---- GEMM1 (m97 structure, depth-2) + fused GLU -> act bf16 ----
// 4 waves, tile 128 rows x (64 gate + 64 up cols), BK=32, vmcnt(4).
// 1-D grid, XCD-chunked swizzle, mtile fastest (B-panel sharers contiguous).
__global__ __launch_bounds__(256, 4) void gemm_gu(
    const unsigned short* __restrict__ xb, const unsigned short* __restrict__ gupt,
    const float* __restrict__ gub, const int* __restrict__ counts,
    const int* __restrict__ rows, unsigned short* __restrict__ act) {
  const int swz = (blockIdx.x & 7) * (4096 / 8) + (blockIdx.x >> 3);
  const int mtile = swz & 15;
  const int ntile = (swz >> 4) & 31;
  const int e = swz >> 9;
  const int count = counts[e];
  if (mtile * 128 >= count) return;
  const int* rl = rows + e * TT + mtile * 128;
  __shared__ __align__(16) char smem[33280];
  unsigned short* As = (unsigned short*)smem;            // [2][4096] bf16
  unsigned short* Bs = (unsigned short*)(smem + 16384);  // [2][4096] bf16
  float* glds = (float*)smem;                            // [128][65] epilogue overlay
  const int tid = threadIdx.x;
  const int lane = tid & 63, wave = tid >> 6;
  const int wm = (wave & 1) << 6, wn = (wave >> 1) << 6;
  const int quad = lane >> 4, r16 = lane & 15;

  // staging: instr q=wave*2+r covers rows q*16+(lane>>2), 16B at (lane&3)*16
  const int lrow = lane >> 2, lko = (lane & 3) * 8;
  const int q0 = wave * 2, q1 = q0 + 1;
  const int row0 = q0 * 16 + lrow, row1 = q1 * 16 + lrow;
  const int last = count - 1 - mtile * 128;
  const int cr0 = row0 <= last ? row0 : last;
  const int cr1 = row1 <= last ? row1 : last;
  const unsigned short* pA0 = xb + (size_t)(rl[cr0] >> 1) * HH + lko;
  const unsigned short* pA1 = xb + (size_t)(rl[cr1] >> 1) * HH + lko;
  const int bn0 = (row0 < 64) ? (ntile * 64 + row0) : (II + ntile * 64 + row0 - 64);
  const int bn1 = (row1 < 64) ? (ntile * 64 + row1) : (II + ntile * 64 + row1 - 64);
  const unsigned short* pB0 = gupt + (size_t)e * N1 * HH + (size_t)bn0 * HH + lko;
  const unsigned short* pB1 = gupt + (size_t)e * N1 * HH + (size_t)bn1 * HH + lko;
  unsigned short* dA0 = As + q0 * 512;  // wave-uniform LDS dests
  unsigned short* dA1 = As + q1 * 512;
  unsigned short* dB0 = Bs + q0 * 512;
  unsigned short* dB1 = Bs + q1 * 512;

  floatx4 acc[4][4] = {};
  const int NTK = HH / 32;  // 32

#define STAGE(B, kk) do { \
    const int ko_ = (kk) * 32; \
    gload16(pA0 + ko_, dA0 + (B) * 4096); \
    gload16(pA1 + ko_, dA1 + (B) * 4096); \
    gload16(pB0 + ko_, dB0 + (B) * 4096); \
    gload16(pB1 + ko_, dB1 + (B) * 4096); \
  } while (0)

#define PHASE(B) do { \
    asm volatile("s_waitcnt vmcnt(4)" ::: "memory"); \
    __builtin_amdgcn_s_barrier(); \
    short8 af[4], bf4[4]; \
    _Pragma("unroll") for (int i = 0; i < 4; i++) \
      af[i] = *(const short8*)(As + (B) * 4096 + (wm + i * 16 + r16) * 32 + quad * 8); \
    _Pragma("unroll") for (int j = 0; j < 4; j++) \
      bf4[j] = *(const short8*)(Bs + (B) * 4096 + (wn + j * 16 + r16) * 32 + quad * 8); \
    asm volatile("s_waitcnt lgkmcnt(0)" ::: "memory"); \
    __builtin_amdgcn_sched_barrier(0); \
    __builtin_amdgcn_s_barrier(); \
    { const int ks_ = kn < NTK ? kn : NTK - 1; kn++; STAGE(B, ks_); } \
    __builtin_amdgcn_sched_barrier(0); \
    __builtin_amdgcn_s_setprio(1); \
    _Pragma("unroll") for (int i = 0; i < 4; i++) \
      _Pragma("unroll") for (int j = 0; j < 4; j++) \
        acc[i][j] = __builtin_amdgcn_mfma_f32_16x16x32_bf16(af[i], bf4[j], acc[i][j], 0, 0, 0); \
    __builtin_amdgcn_s_setprio(0); \
  } while (0)

  STAGE(0, 0);
  STAGE(1, 1);
  int kn = 2;
#pragma unroll 1
  for (int t = 0; t < NTK; t += 2) {
    PHASE(0);
    PHASE(1);
  }
  asm volatile("s_waitcnt vmcnt(0)" ::: "memory");
  __builtin_amdgcn_s_barrier();

  // epilogue: gate waves (wn==0) -> glu to LDS; up waves -> act bf16
  const int colbase = ntile * 64;
  if (wn == 0) {
#pragma unroll
    for (int j = 0; j < 4; j++) {
      const int c = j * 16 + r16;
      const float gb = gub[e * N1 + colbase + c];
#pragma unroll
      for (int i = 0; i < 4; i++)
#pragma unroll
        for (int reg = 0; reg < 4; reg++) {
          const int rr = wm + i * 16 + quad * 4 + reg;
          float g = acc[i][j][reg] + gb;
          g = fminf(g, LIMIT);
          glds[rr * 65 + c] = g / (1.f + expf(-g * ALPHA));
        }
    }
  }
  __builtin_amdgcn_s_barrier();
  if (wn == 64) {
#pragma unroll
    for (int j = 0; j < 4; j++) {
      const int c = j * 16 + r16;
      const float ub = gub[e * N1 + II + colbase + c];
#pragma unroll
      for (int i = 0; i < 4; i++)
#pragma unroll
        for (int reg = 0; reg < 4; reg++) {
          const int rr = wm + i * 16 + quad * 4 + reg;
          if (mtile * 128 + rr < count) {
            float u = acc[i][j][reg] + ub;
            u = fminf(fmaxf(u, -LIMIT), LIMIT);
            const float glu = glds[rr * 65 + c];
            act[(size_t)rl[rr] * II + colbase + c] = (unsigned short)f2bf((u + 1.f) * glu);
          }
        }
    }
  }
#undef STAGE
#undef PHASE
}

// ---- GEMM2 (depth-2): act bf16 x dp_t bf16, split-K=2,
//      epilogue scales by topk_w and atomicAdds into out ----
__global__ __launch_bounds__(256, 4) void gemm_down(
    const unsigned short* __restrict__ act, const unsigned short* __restrict__ dpt,
    const float* __restrict__ db, const int* __restrict__ counts,
    const int* __restrict__ rows, const float* __restrict__ tw,
    float* __restrict__ out) {
  const int swz = (blockIdx.x & 7) * (2048 / 8) + (blockIdx.x >> 3);
  const int mtile = swz & 15;
  const int ntile = (swz >> 4) & 7;
  const int e = swz >> 8, kc = (swz >> 7) & 1;
  const int count = counts[e];
  if (mtile * 128 >= count) return;
  const int kb = kc * (II / 2);  // 1024-wide K chunk
  const int* rl = rows + e * TT + mtile * 128;
  __shared__ __align__(16) char smem[32768];
  unsigned short* As = (unsigned short*)smem;            // [2][4096]
  unsigned short* Bs = (unsigned short*)(smem + 16384);  // [2][4096]
  const int tid = threadIdx.x;
  const int lane = tid & 63, wave = tid >> 6;
  const int wm = (wave & 1) << 6, wn = (wave >> 1) << 6;
  const int quad = lane >> 4, r16 = lane & 15;

  const int lrow = lane >> 2, lko = (lane & 3) * 8;
  const int q0 = wave * 2, q1 = q0 + 1;
  const int row0 = q0 * 16 + lrow, row1 = q1 * 16 + lrow;
  const int last = count - 1 - mtile * 128;
  const int cr0 = row0 <= last ? row0 : last;
  const int cr1 = row1 <= last ? row1 : last;
  const unsigned short* pA0 = act + (size_t)rl[cr0] * II + kb + lko;
  const unsigned short* pA1 = act + (size_t)rl[cr1] * II + kb + lko;
  const unsigned short* pB0 = dpt + (size_t)e * HH * II + (size_t)(ntile * 128 + row0) * II + kb + lko;
  const unsigned short* pB1 = dpt + (size_t)e * HH * II + (size_t)(ntile * 128 + row1) * II + kb + lko;
  unsigned short* dA0 = As + q0 * 512;
  unsigned short* dA1 = As + q1 * 512;
  unsigned short* dB0 = Bs + q0 * 512;
  unsigned short* dB1 = Bs + q1 * 512;

  floatx4 acc[4][4] = {};
  const int NTK = (II / 2) / 32;  // 32

#define STAGE(B, kk) do { \
    const int ko_ = (kk) * 32; \
    gload16(pA0 + ko_, dA0 + (B) * 4096); \
    gload16(pA1 + ko_, dA1 + (B) * 4096); \
    gload16(pB0 + ko_, dB0 + (B) * 4096); \
    gload16(pB1 + ko_, dB1 + (B) * 4096); \
  } while (0)

#define PHASE(B) do { \
    asm volatile("s_waitcnt vmcnt(4)" ::: "memory"); \
    __builtin_amdgcn_s_barrier(); \
    short8 af[4], bf4[4]; \
    _Pragma("unroll") for (int i = 0; i < 4; i++) \
      af[i] = *(const short8*)(As + (B) * 4096 + (wm + i * 16 + r16) * 32 + quad * 8); \
    _Pragma("unroll") for (int j = 0; j < 4; j++) \
      bf4[j] = *(const short8*)(Bs + (B) * 4096 + (wn + j * 16 + r16) * 32 + quad * 8); \
    asm volatile("s_waitcnt lgkmcnt(0)" ::: "memory"); \
    __builtin_amdgcn_sched_barrier(0); \
    __builtin_amdgcn_s_barrier(); \
    { const int ks_ = kn < NTK ? kn : NTK - 1; kn++; STAGE(B, ks_); } \
    __builtin_amdgcn_sched_barrier(0); \
    __builtin_amdgcn_s_setprio(1); \
    _Pragma("unroll") for (int i = 0; i < 4; i++) \
      _Pragma("unroll") for (int j = 0; j < 4; j++) \
        acc[i][j] = __builtin_amdgcn_mfma_f32_16x16x32_bf16(af[i], bf4[j], acc[i][j], 0, 0, 0); \
    __builtin_amdgcn_s_setprio(0); \
  } while (0)

  STAGE(0, 0);
  STAGE(1, 1);
  int kn = 2;
#pragma unroll 1
  for (int t = 0; t < NTK; t += 2) {
    PHASE(0);
    PHASE(1);
  }
  asm volatile("s_waitcnt vmcnt(0)" ::: "memory");
  __builtin_amdgcn_s_barrier();

#pragma unroll
  for (int i = 0; i < 4; i++) {
#pragma unroll
    for (int reg = 0; reg < 4; reg++) {
      const int rr = wm + i * 16 + quad * 4 + reg;
      if (mtile * 128 + rr < count) {
        const int ent = rl[rr];
        const float w = tw[ent];
        float* orow = out + (size_t)(ent >> 1) * HH + ntile * 128;
#pragma unroll
        for (int j = 0; j < 4; j++) {
          const int c = wn + j * 16 + r16;
          float v = acc[i][j][reg];
          if (kc == 0) v += db[e * HH + ntile * 128 + c];
          atomicAdd(&orow[c], w * v);
        }
      }
    }
  }
#undef STAGE
#undef PHASE
}

extern "C" void kernel_launch(void* const* d_in, const int* in_sizes, int n_in,
                              void* d_out, int out_size, void* d_ws, size_t ws_size,
                              hipStream_t stream) {
  const float* x   = (const float*)d_in[0];
  const float* rw  = (const float*)d_in[1];
  const float* rb  = (const float*)d_in[2];
  const float* gup = (const float*)d_in[3];
  const float* gub = (const float*)d_in[4];
  const float* dp  = (const float*)d_in[5];
  const float* db  = (const float*)d_in[6];
  float* out = (float*)d_out;

  char* ws = (char*)d_ws;
  float* topk_w   = (float*)(ws + 0);                      // 16 KB
  int*   counts   = (int*)(ws + 16384);                    // 256 B
  int*   rows     = (int*)(ws + 16640);                    // 64 KB
  unsigned short* xb   = (unsigned short*)(ws + 131072);               // 4 MB
  unsigned short* gupt = (unsigned short*)(ws + 4325376);              // 67.1 MB
  unsigned short* dpt  = (unsigned short*)(ws + 71434240);             // 33.6 MB
  unsigned short* act  = (unsigned short*)(ws + 104988672);            // 16.8 MB

  transpose_all<<<12288, 256, 0, stream>>>(gup, dp, gupt, dpt, counts);
  router_kernel<<<TT, 256, 0, stream>>>(x, rw, rb, topk_w, counts, rows, xb, out);
  gemm_gu<<<4096, 256, 0, stream>>>(xb, gupt, gub, counts, rows, act);
  gemm_down<<<2048, 256, 0, stream>>>(act, dpt, db, counts, rows, topk_w, out);
}